// Round 10
// baseline (274.842 us; speedup 1.0000x reference)
//
#include <hip/hip_runtime.h>
#include <math.h>

#define NEG_SLOPE 0.2f
#define SCAN_CHUNK 2048     // per-block elements in hierarchical scan (256 thr * 8)
#define ECLAMP 80.0f        // exp() inf-safety clamp (never hit statistically)
#define BUCKET_SHIFT 7      // 128 nodes per bucket
#define BUCKET_MASK 127
#define NPB 128             // nodes per bucket
#define NBMAX 1024          // max buckets (N <= 131072)
#define EB_CHUNK 4096       // edges per partition block (256 thr * 16)

__device__ __forceinline__ float lrelu(float e) {
    return e > 0.f ? e : NEG_SLOPE * e;
}

// ---------------- Layer-1 node prep: as1[N,2], ad1[N,2] (h1 never stored) ---
// 32 threads per node; lane c owns channel c (head = c>>4).
__global__ void k0_prep1(const float* __restrict__ x,
                         const float* __restrict__ W1,
                         const float* __restrict__ a_src1,
                         const float* __restrict__ a_dst1,
                         float* __restrict__ as1,
                         float* __restrict__ ad1,
                         int N) {
    int t = blockIdx.x * blockDim.x + threadIdx.x;
    int n = t >> 5;
    int c = t & 31;
    if (n >= N) return;
    const float4 xv = reinterpret_cast<const float4*>(x)[n];
    float h = xv.x * W1[c] + xv.y * W1[32 + c] + xv.z * W1[64 + c] + xv.w * W1[96 + c];
    float ts = h * a_src1[c];
    float td = h * a_dst1[c];
#pragma unroll
    for (int m = 8; m >= 1; m >>= 1) {        // reduce over 16 channels of this head
        ts += __shfl_xor(ts, m);
        td += __shfl_xor(td, m);
    }
    if ((c & 15) == 0) {
        int hh = c >> 4;
        as1[n * 2 + hh] = ts;
        ad1[n * 2 + hh] = td;
    }
}

// ---------------- edge partition: two-level counting sort (buckets only) ----
__global__ void p1_hist(const int* __restrict__ dst, int* __restrict__ cmatT,
                        int E, int NB, int nblkE) {
    __shared__ int cnt[NBMAX];
    const int blk = blockIdx.x, tid = threadIdx.x;
    for (int b = tid; b < NB; b += 256) cnt[b] = 0;
    __syncthreads();
    int base = blk * EB_CHUNK;
    int end = min(base + EB_CHUNK, E);
    for (int e = base + tid; e < end; e += 256)
        atomicAdd(&cnt[dst[e] >> BUCKET_SHIFT], 1);
    __syncthreads();
    for (int b = tid; b < NB; b += 256)
        cmatT[(size_t)b * nblkE + blk] = cnt[b];
}

// --------- hierarchical exclusive scan (generic, over n ints) ---------------
__global__ void k2a_partials(const int* __restrict__ in, int* __restrict__ bsum, int n) {
    __shared__ int ws[4];
    const int tid = threadIdx.x;
    const int lane = tid & 63, wid = tid >> 6;
    int base = blockIdx.x * SCAN_CHUNK + tid * 8;
    int lsum = 0;
#pragma unroll
    for (int i = 0; i < 8; ++i) {
        int idx = base + i;
        lsum += (idx < n) ? in[idx] : 0;
    }
#pragma unroll
    for (int m = 32; m >= 1; m >>= 1) lsum += __shfl_xor(lsum, m);
    if (lane == 0) ws[wid] = lsum;
    __syncthreads();
    if (tid == 0) bsum[blockIdx.x] = ws[0] + ws[1] + ws[2] + ws[3];
}

__global__ void k2b_scanb(const int* __restrict__ bsum, int* __restrict__ bscan, int nb) {
    __shared__ int wsum[16];
    const int tid = threadIdx.x;
    const int lane = tid & 63, wid = tid >> 6;
    int carry = 0;
    for (int base = 0; base < nb; base += 1024) {
        int i = base + tid;
        int v = (i < nb) ? bsum[i] : 0;
        int xx = v;
#pragma unroll
        for (int off = 1; off < 64; off <<= 1) {
            int t = __shfl_up(xx, off);
            if (lane >= off) xx += t;
        }
        if (lane == 63) wsum[wid] = xx;
        __syncthreads();
        int woff = 0;
        for (int w = 0; w < wid; ++w) woff += wsum[w];
        if (i < nb) bscan[i] = carry + woff + xx - v;
        int tot = 0;
        for (int w = 0; w < 16; ++w) tot += wsum[w];
        carry += tot;
        __syncthreads();
    }
}

__global__ void k2c_scan(const int* __restrict__ in, const int* __restrict__ bscan,
                         int* __restrict__ out, int n) {
    __shared__ int ws[4];
    const int tid = threadIdx.x;
    const int lane = tid & 63, wid = tid >> 6;
    int base = blockIdx.x * SCAN_CHUNK + tid * 8;
    int v[8], pre[8];
    int lsum = 0;
#pragma unroll
    for (int i = 0; i < 8; ++i) {
        int idx = base + i;
        v[i] = (idx < n) ? in[idx] : 0;
        pre[i] = lsum;
        lsum += v[i];
    }
    int xs = lsum;
#pragma unroll
    for (int off = 1; off < 64; off <<= 1) {
        int t = __shfl_up(xs, off);
        if (lane >= off) xs += t;
    }
    if (lane == 63) ws[wid] = xs;
    __syncthreads();
    int woff = 0;
    for (int w = 0; w < wid; ++w) woff += ws[w];
    int off0 = bscan[blockIdx.x] + woff + xs - lsum;
#pragma unroll
    for (int i = 0; i < 8; ++i) {
        int idx = base + i;
        if (idx < n) out[idx] = off0 + pre[i];
    }
}

// P3: scatter edges into bucket-partitioned ebuf via LDS cursors
__global__ void p3_scatter(const int* __restrict__ src, const int* __restrict__ dst,
                           const int* __restrict__ cscan, unsigned int* __restrict__ ebuf,
                           int E, int NB, int nblkE) {
    __shared__ int cur[NBMAX];
    const int blk = blockIdx.x, tid = threadIdx.x;
    for (int b = tid; b < NB; b += 256)
        cur[b] = cscan[(size_t)b * nblkE + blk];
    __syncthreads();
    int base = blk * EB_CHUNK;
    int end = min(base + EB_CHUNK, E);
    for (int e = base + tid; e < end; e += 256) {
        int d = dst[e];
        int b = d >> BUCKET_SHIFT;
        int pos = atomicAdd(&cur[b], 1);
        ebuf[pos] = (unsigned int)src[e] | ((unsigned int)(d & BUCKET_MASK) << 24);
    }
}

// ---------------- A1: layer-1 edge-parallel aggregation + fused epilogue ----
// One block per 128-node bucket. Edges accumulate (s, g[4]) per (node, head)
// into LDS via ds_add_f32 (no return). Epilogue: self-loop + /s + @W1 + b1 +
// ELU + @W2 -> h2p(t0,t1,as2), ad2.
__global__ void a1_layer1(const unsigned int* __restrict__ ebuf,
                          const int* __restrict__ cscan,
                          const float* __restrict__ x, const float* __restrict__ as1,
                          const float* __restrict__ ad1, const float* __restrict__ b1,
                          const float* __restrict__ W1, const float* __restrict__ W2,
                          const float* __restrict__ a_src2, const float* __restrict__ a_dst2,
                          float4* __restrict__ h2p, float* __restrict__ ad2,
                          int N, int E, int NB, int nblkE) {
    __shared__ float acc[NPB][10];     // [s0, g0x,g0y,g0z,g0w, s1, g1x,g1y,g1z,g1w]
    __shared__ float2 adL[NPB];
    const int b = blockIdx.x, tid = threadIdx.x;
    const float2* as1v = reinterpret_cast<const float2*>(as1);
    const float2* ad1v = reinterpret_cast<const float2*>(ad1);
    const float4* x4 = reinterpret_cast<const float4*>(x);
    int bstart = cscan[(size_t)b * nblkE];
    int bend = (b + 1 < NB) ? cscan[(size_t)(b + 1) * nblkE] : E;
    int node0 = b << BUCKET_SHIFT;
    if (tid < NPB) {
#pragma unroll
        for (int k = 0; k < 10; ++k) acc[tid][k] = 0.f;
        int node = node0 + tid;
        adL[tid] = (node < N) ? ad1v[node] : make_float2(0.f, 0.f);
    }
    __syncthreads();
    for (int i = bstart + tid; i < bend; i += 256) {
        unsigned int ev = ebuf[i];
        int dl = ev >> 24;
        int srcn = ev & 0x00FFFFFF;
        float2 av = as1v[srcn];            // 8B random gather (L2-hot, 800KB)
        float4 xv = x4[srcn];              // 16B random gather (L2-hot, 1.6MB)
        float2 adv = adL[dl];
        float w0 = __expf(fminf(lrelu(av.x + adv.x), ECLAMP));
        float w1 = __expf(fminf(lrelu(av.y + adv.y), ECLAMP));
        float* a = acc[dl];
        atomicAdd(&a[0], w0);
        atomicAdd(&a[1], w0 * xv.x);
        atomicAdd(&a[2], w0 * xv.y);
        atomicAdd(&a[3], w0 * xv.z);
        atomicAdd(&a[4], w0 * xv.w);
        atomicAdd(&a[5], w1);
        atomicAdd(&a[6], w1 * xv.x);
        atomicAdd(&a[7], w1 * xv.y);
        atomicAdd(&a[8], w1 * xv.z);
        atomicAdd(&a[9], w1 * xv.w);
    }
    __syncthreads();
    if (tid < NPB) {
        int n = node0 + tid;
        if (n < N) {
            float2 asv = as1v[n];
            float2 adv = adL[tid];
            float4 xv = x4[n];
            float w0 = __expf(fminf(lrelu(asv.x + adv.x), ECLAMP));
            float w1 = __expf(fminf(lrelu(asv.y + adv.y), ECLAMP));
            float s0 = acc[tid][0] + w0;
            float s1 = acc[tid][5] + w1;
            float ag[2][4];
            ag[0][0] = (acc[tid][1] + w0 * xv.x) / s0;
            ag[0][1] = (acc[tid][2] + w0 * xv.y) / s0;
            ag[0][2] = (acc[tid][3] + w0 * xv.z) / s0;
            ag[0][3] = (acc[tid][4] + w0 * xv.w) / s0;
            ag[1][0] = (acc[tid][6] + w1 * xv.x) / s1;
            ag[1][1] = (acc[tid][7] + w1 * xv.y) / s1;
            ag[1][2] = (acc[tid][8] + w1 * xv.z) / s1;
            ag[1][3] = (acc[tid][9] + w1 * xv.w) / s1;
            float t0 = 0.f, t1 = 0.f;
#pragma unroll
            for (int c = 0; c < 32; ++c) {
                const float* g = ag[c >> 4];
                float o = b1[c] + g[0] * W1[c] + g[1] * W1[32 + c]
                        + g[2] * W1[64 + c] + g[3] * W1[96 + c];
                o = o > 0.f ? o : expm1f(o);       // ELU
                t0 += o * W2[c * 2 + 0];
                t1 += o * W2[c * 2 + 1];
            }
            float as2v = t0 * a_src2[0] + t1 * a_src2[1];
            float ad2v = t0 * a_dst2[0] + t1 * a_dst2[1];
            h2p[n] = make_float4(t0, t1, as2v, 0.f);
            ad2[n] = ad2v;
        }
    }
}

// ---------------- A2: layer-2 edge-parallel aggregation -> output -----------
__global__ void a2_layer2(const unsigned int* __restrict__ ebuf,
                          const int* __restrict__ cscan,
                          const float4* __restrict__ h2p, const float* __restrict__ ad2,
                          const float* __restrict__ b2,
                          float* __restrict__ out,
                          int N, int E, int NB, int nblkE) {
    __shared__ float acc[NPB][3];      // [s, x, y]
    __shared__ float adL[NPB];
    const int b = blockIdx.x, tid = threadIdx.x;
    int bstart = cscan[(size_t)b * nblkE];
    int bend = (b + 1 < NB) ? cscan[(size_t)(b + 1) * nblkE] : E;
    int node0 = b << BUCKET_SHIFT;
    if (tid < NPB) {
        acc[tid][0] = 0.f; acc[tid][1] = 0.f; acc[tid][2] = 0.f;
        int node = node0 + tid;
        adL[tid] = (node < N) ? ad2[node] : 0.f;
    }
    __syncthreads();
    for (int i = bstart + tid; i < bend; i += 256) {
        unsigned int ev = ebuf[i];
        int dl = ev >> 24;
        int srcn = ev & 0x00FFFFFF;
        float4 hv = h2p[srcn];             // 16B random gather (L2-hot, 1.6MB)
        float w = __expf(fminf(lrelu(hv.z + adL[dl]), ECLAMP));
        float* a = acc[dl];
        atomicAdd(&a[0], w);
        atomicAdd(&a[1], w * hv.x);
        atomicAdd(&a[2], w * hv.y);
    }
    __syncthreads();
    if (tid < NPB) {
        int n = node0 + tid;
        if (n < N) {
            float4 hv = h2p[n];
            float w = __expf(fminf(lrelu(hv.z + adL[tid]), ECLAMP));
            float s = acc[tid][0] + w;
            float2 o;
            o.x = (acc[tid][1] + w * hv.x) / s + b2[0];
            o.y = (acc[tid][2] + w * hv.y) / s + b2[1];
            reinterpret_cast<float2*>(out)[n] = o;
        }
    }
}

extern "C" void kernel_launch(void* const* d_in, const int* in_sizes, int n_in,
                              void* d_out, int out_size, void* d_ws, size_t ws_size,
                              hipStream_t stream) {
    const float* x      = (const float*)d_in[0];
    const int*   ei     = (const int*)d_in[1];
    const float* W1     = (const float*)d_in[2];
    const float* a_src1 = (const float*)d_in[3];
    const float* a_dst1 = (const float*)d_in[4];
    const float* b1     = (const float*)d_in[5];
    const float* W2     = (const float*)d_in[6];
    const float* a_src2 = (const float*)d_in[7];
    const float* a_dst2 = (const float*)d_in[8];
    const float* b2     = (const float*)d_in[9];
    float* out = (float*)d_out;

    const int N = in_sizes[0] / 4;
    const int E = in_sizes[1] / 2;
    const int* srcp = ei;
    const int* dstp = ei + E;

    const int NB    = (N + BUCKET_MASK) >> BUCKET_SHIFT;   // 128-node buckets
    const int nblkE = (E + EB_CHUNK - 1) / EB_CHUNK;       // edge partition blocks
    const int M     = NB * nblkE;
    const int nb2   = (M + SCAN_CHUNK - 1) / SCAN_CHUNK;

    // workspace layout (h2p first for 16B alignment)
    char* w = (char*)d_ws;
    float4* h2p  = (float4*)w;  w += (size_t)N * sizeof(float4);
    float*  as1  = (float*)w;   w += (size_t)N * 2 * sizeof(float);
    float*  ad1  = (float*)w;   w += (size_t)N * 2 * sizeof(float);
    float*  ad2  = (float*)w;   w += (size_t)N * sizeof(float);
    int* cmatT  = (int*)w;      w += (size_t)M * sizeof(int);
    int* cscan  = (int*)w;      w += (size_t)M * sizeof(int);
    int* bsum   = (int*)w;      w += (size_t)(nb2 + 4) * sizeof(int);
    int* bscan  = (int*)w;      w += (size_t)(nb2 + 4) * sizeof(int);
    unsigned int* ebuf = (unsigned int*)w;  w += (size_t)E * sizeof(unsigned int);

    const int BT = 256;
    k0_prep1<<<((size_t)N * 32 + BT - 1) / BT, BT, 0, stream>>>(
        x, W1, a_src1, a_dst1, as1, ad1, N);
    p1_hist<<<nblkE, 256, 0, stream>>>(dstp, cmatT, E, NB, nblkE);
    k2a_partials<<<nb2, 256, 0, stream>>>(cmatT, bsum, M);
    k2b_scanb<<<1, 1024, 0, stream>>>(bsum, bscan, nb2);
    k2c_scan<<<nb2, 256, 0, stream>>>(cmatT, bscan, cscan, M);
    p3_scatter<<<nblkE, 256, 0, stream>>>(srcp, dstp, cscan, ebuf, E, NB, nblkE);
    a1_layer1<<<NB, 256, 0, stream>>>(ebuf, cscan, x, as1, ad1, b1, W1, W2,
                                      a_src2, a_dst2, h2p, ad2, N, E, NB, nblkE);
    a2_layer2<<<NB, 256, 0, stream>>>(ebuf, cscan, h2p, ad2, b2, out, N, E, NB, nblkE);
}

// Round 12
// 182.786 us; speedup vs baseline: 1.5036x; 1.5036x over previous
//
#include <hip/hip_runtime.h>
#include <math.h>

#define NEG_SLOPE 0.2f
#define SCAN_CHUNK 2048     // per-block elements in hierarchical scan (256 thr * 8)
#define ECLAMP 80.0f        // exp() inf-safety clamp (never hit statistically)
#define BUCKET_SHIFT 7      // 128 nodes per bucket
#define BUCKET_MASK 127
#define NPB 128             // nodes per bucket
#define NBMAX 1024          // max buckets (N <= 131072)
#define EB_CHUNK 2048       // edges per partition block (256 thr * 8)
#define P4_CAP 3072         // LDS edge cache per bucket (avg 2048, +20 sigma)

__device__ __forceinline__ float lrelu(float e) {
    return e > 0.f ? e : NEG_SLOPE * e;
}

// ---------------- Layer-1 node prep: as1[N,2], ad1[N,2] (h1 never stored) ---
// 32 threads per node; lane c owns channel c (head = c>>4).
__global__ void k0_prep1(const float* __restrict__ x,
                         const float* __restrict__ W1,
                         const float* __restrict__ a_src1,
                         const float* __restrict__ a_dst1,
                         float* __restrict__ as1,
                         float* __restrict__ ad1,
                         int N) {
    int t = blockIdx.x * blockDim.x + threadIdx.x;
    int n = t >> 5;
    int c = t & 31;
    if (n >= N) return;
    const float4 xv = reinterpret_cast<const float4*>(x)[n];
    float h = xv.x * W1[c] + xv.y * W1[32 + c] + xv.z * W1[64 + c] + xv.w * W1[96 + c];
    float ts = h * a_src1[c];
    float td = h * a_dst1[c];
#pragma unroll
    for (int m = 8; m >= 1; m >>= 1) {        // reduce over 16 channels of this head
        ts += __shfl_xor(ts, m);
        td += __shfl_xor(td, m);
    }
    if ((c & 15) == 0) {
        int hh = c >> 4;
        as1[n * 2 + hh] = ts;
        ad1[n * 2 + hh] = td;
    }
}

// ---------------- edge partition: two-level counting sort -------------------
__global__ void p1_hist(const int* __restrict__ dst, int* __restrict__ cmatT,
                        int E, int NB, int nblkE) {
    __shared__ int cnt[NBMAX];
    const int blk = blockIdx.x, tid = threadIdx.x;
    for (int b = tid; b < NB; b += 256) cnt[b] = 0;
    __syncthreads();
    int base = blk * EB_CHUNK;
    int end = min(base + EB_CHUNK, E);
    for (int e = base + tid; e < end; e += 256)
        atomicAdd(&cnt[dst[e] >> BUCKET_SHIFT], 1);
    __syncthreads();
    for (int b = tid; b < NB; b += 256)
        cmatT[(size_t)b * nblkE + blk] = cnt[b];
}

// --------- hierarchical exclusive scan (generic, over n ints) ---------------
__global__ void k2a_partials(const int* __restrict__ in, int* __restrict__ bsum, int n) {
    __shared__ int ws[4];
    const int tid = threadIdx.x;
    const int lane = tid & 63, wid = tid >> 6;
    int base = blockIdx.x * SCAN_CHUNK + tid * 8;
    int lsum = 0;
#pragma unroll
    for (int i = 0; i < 8; ++i) {
        int idx = base + i;
        lsum += (idx < n) ? in[idx] : 0;
    }
#pragma unroll
    for (int m = 32; m >= 1; m >>= 1) lsum += __shfl_xor(lsum, m);
    if (lane == 0) ws[wid] = lsum;
    __syncthreads();
    if (tid == 0) bsum[blockIdx.x] = ws[0] + ws[1] + ws[2] + ws[3];
}

__global__ void k2b_scanb(const int* __restrict__ bsum, int* __restrict__ bscan, int nb) {
    __shared__ int wsum[16];
    const int tid = threadIdx.x;
    const int lane = tid & 63, wid = tid >> 6;
    int carry = 0;
    for (int base = 0; base < nb; base += 1024) {
        int i = base + tid;
        int v = (i < nb) ? bsum[i] : 0;
        int xx = v;
#pragma unroll
        for (int off = 1; off < 64; off <<= 1) {
            int t = __shfl_up(xx, off);
            if (lane >= off) xx += t;
        }
        if (lane == 63) wsum[wid] = xx;
        __syncthreads();
        int woff = 0;
        for (int w = 0; w < wid; ++w) woff += wsum[w];
        if (i < nb) bscan[i] = carry + woff + xx - v;
        int tot = 0;
        for (int w = 0; w < 16; ++w) tot += wsum[w];
        carry += tot;
        __syncthreads();
    }
}

__global__ void k2c_scan(const int* __restrict__ in, const int* __restrict__ bscan,
                         int* __restrict__ out, int n) {
    __shared__ int ws[4];
    const int tid = threadIdx.x;
    const int lane = tid & 63, wid = tid >> 6;
    int base = blockIdx.x * SCAN_CHUNK + tid * 8;
    int v[8], pre[8];
    int lsum = 0;
#pragma unroll
    for (int i = 0; i < 8; ++i) {
        int idx = base + i;
        v[i] = (idx < n) ? in[idx] : 0;
        pre[i] = lsum;
        lsum += v[i];
    }
    int xs = lsum;
#pragma unroll
    for (int off = 1; off < 64; off <<= 1) {
        int t = __shfl_up(xs, off);
        if (lane >= off) xs += t;
    }
    if (lane == 63) ws[wid] = xs;
    __syncthreads();
    int woff = 0;
    for (int w = 0; w < wid; ++w) woff += ws[w];
    int off0 = bscan[blockIdx.x] + woff + xs - lsum;
#pragma unroll
    for (int i = 0; i < 8; ++i) {
        int idx = base + i;
        if (idx < n) out[idx] = off0 + pre[i];
    }
}

// P3: scatter edges into bucket-partitioned ebuf via LDS cursors
__global__ void p3_scatter(const int* __restrict__ src, const int* __restrict__ dst,
                           const int* __restrict__ cscan, unsigned int* __restrict__ ebuf,
                           int E, int NB, int nblkE) {
    __shared__ int cur[NBMAX];
    const int blk = blockIdx.x, tid = threadIdx.x;
    for (int b = tid; b < NB; b += 256)
        cur[b] = cscan[(size_t)b * nblkE + blk];
    __syncthreads();
    int base = blk * EB_CHUNK;
    int end = min(base + EB_CHUNK, E);
    for (int e = base + tid; e < end; e += 256) {
        int d = dst[e];
        int b = d >> BUCKET_SHIFT;
        int pos = atomicAdd(&cur[b], 1);
        ebuf[pos] = (unsigned int)src[e] | ((unsigned int)(d & BUCKET_MASK) << 24);
    }
}

// P4: per-bucket CSR finalize: LDS-cached hist -> local scan -> rp + esrt
__global__ void p4_csr(const unsigned int* __restrict__ ebuf,
                       const int* __restrict__ cscan,
                       int* __restrict__ rp, int* __restrict__ esrt,
                       int N, int E, int NB, int nblkE) {
    __shared__ unsigned int ecache[P4_CAP];
    __shared__ int degl[NPB];
    __shared__ int curl[NPB];
    __shared__ int wsum[4];
    const int b = blockIdx.x, tid = threadIdx.x;
    const int lane = tid & 63, wid = tid >> 6;
    int bstart = cscan[(size_t)b * nblkE];
    int bend = (b + 1 < NB) ? cscan[(size_t)(b + 1) * nblkE] : E;
    int cnt = bend - bstart;
    if (tid < NPB) degl[tid] = 0;
    __syncthreads();
    for (int i = tid; i < cnt; i += 256) {
        unsigned int ev = ebuf[bstart + i];
        if (i < P4_CAP) ecache[i] = ev;       // cache for the scatter pass
        atomicAdd(&degl[ev >> 24], 1);
    }
    __syncthreads();
    int v = (tid < NPB) ? degl[tid] : 0;
    int xs = v;
#pragma unroll
    for (int off = 1; off < 64; off <<= 1) {
        int t = __shfl_up(xs, off);
        if (lane >= off) xs += t;
    }
    if (lane == 63) wsum[wid] = xs;
    __syncthreads();
    int woff = 0;
    for (int w = 0; w < wid; ++w) woff += wsum[w];
    int excl = woff + xs - v;
    int node = (b << BUCKET_SHIFT) + tid;
    if (tid < NPB) {
        if (node < N) rp[node] = bstart + excl;
        curl[tid] = bstart + excl;
    }
    if (b == 0 && tid == 0) rp[N] = E;
    __syncthreads();
    for (int i = tid; i < cnt; i += 256) {
        unsigned int ev = (i < P4_CAP) ? ecache[i] : ebuf[bstart + i];
        int dl = ev >> 24;
        int pos = atomicAdd(&curl[dl], 1);
        esrt[pos] = (int)(ev & 0x00FFFFFFu);
    }
}

// ---------------- Layer-1 aggregate in x-space + fused epilogue --------------
// 8 lanes per node: lane l -> (head h = l>>2, dim d = l&3).
// Aggregates 4-dim x features (h1 = x@W1 is linear), recomputes attention
// weights inline from the L2-hot as1 table. Fused: /s, @W1, +b1, ELU, @W2,
// as2/ad2 -> h2p.
__global__ void k4_layer1(const int* __restrict__ rp, const int* __restrict__ esrt,
                          const float* __restrict__ x, const float* __restrict__ as1,
                          const float* __restrict__ ad1, const float* __restrict__ b1,
                          const float* __restrict__ W1,
                          const float* __restrict__ W2, const float* __restrict__ a_src2,
                          const float* __restrict__ a_dst2,
                          float4* __restrict__ h2p, float* __restrict__ ad2,
                          int N) {
    int t = blockIdx.x * blockDim.x + threadIdx.x;
    int n = t >> 3;
    int l = t & 7;
    if (n >= N) return;
    int h = l >> 2;         // head
    int d = l & 3;          // x-dim
    float ad = ad1[n * 2 + h];
    // self-loop
    float es = lrelu(as1[n * 2 + h] + ad);
    float ws = __expf(fminf(es, ECLAMP));
    float g0 = ws * x[(size_t)n * 4 + d], g1 = 0.f, g2 = 0.f, g3 = 0.f;
    float s0 = ws, s1 = 0.f, s2 = 0.f, s3 = 0.f;

    int p0 = rp[n], p1 = rp[n + 1];
    int p = p0;
    for (; p + 3 < p1; p += 4) {              // 4 independent gather chains
        int sa = esrt[p];
        int sb = esrt[p + 1];
        int sc_ = esrt[p + 2];
        int sd = esrt[p + 3];
        float ea = lrelu(as1[(size_t)sa * 2 + h] + ad);
        float eb = lrelu(as1[(size_t)sb * 2 + h] + ad);
        float ec = lrelu(as1[(size_t)sc_ * 2 + h] + ad);
        float ed = lrelu(as1[(size_t)sd * 2 + h] + ad);
        float xa = x[(size_t)sa * 4 + d];
        float xb = x[(size_t)sb * 4 + d];
        float xc = x[(size_t)sc_ * 4 + d];
        float xd = x[(size_t)sd * 4 + d];
        float wa = __expf(fminf(ea, ECLAMP));
        float wb = __expf(fminf(eb, ECLAMP));
        float wc = __expf(fminf(ec, ECLAMP));
        float wd = __expf(fminf(ed, ECLAMP));
        s0 += wa;  g0 += wa * xa;
        s1 += wb;  g1 += wb * xb;
        s2 += wc;  g2 += wc * xc;
        s3 += wd;  g3 += wd * xd;
    }
    for (; p < p1; ++p) {
        int sa = esrt[p];
        float ea = lrelu(as1[(size_t)sa * 2 + h] + ad);
        float xa = x[(size_t)sa * 4 + d];
        float wa = __expf(fminf(ea, ECLAMP));
        s0 += wa;  g0 += wa * xa;
    }
    float s = (s0 + s1) + (s2 + s3);
    float agg = ((g0 + g1) + (g2 + g3)) / s;   // aggregated x, this (h,d)

    // collect all 8 (h,d) agg values within the 8-lane segment
    float a2[2][4];
#pragma unroll
    for (int k = 0; k < 8; ++k)
        a2[k >> 2][k & 3] = __shfl(agg, k, 8);

    // lane computes channels c = l*4 .. l*4+3
    float t0 = 0.f, t1 = 0.f;
#pragma unroll
    for (int j = 0; j < 4; ++j) {
        int c = l * 4 + j;
        int hc = c >> 4;
        float o = b1[c]
                + a2[hc][0] * W1[c]
                + a2[hc][1] * W1[32 + c]
                + a2[hc][2] * W1[64 + c]
                + a2[hc][3] * W1[96 + c];
        o = o > 0.f ? o : expm1f(o);           // ELU
        t0 += o * W2[c * 2 + 0];
        t1 += o * W2[c * 2 + 1];
    }
#pragma unroll
    for (int msk = 1; msk <= 4; msk <<= 1) {   // reduce over 8-lane segment
        t0 += __shfl_xor(t0, msk);
        t1 += __shfl_xor(t1, msk);
    }
    if (l == 0) {
        float as2v = t0 * a_src2[0] + t1 * a_src2[1];
        float ad2v = t0 * a_dst2[0] + t1 * a_dst2[1];
        h2p[n] = make_float4(t0, t1, as2v, 0.f);
        ad2[n] = ad2v;
    }
}

// ---------------- Layer-2 aggregate → output --------------------------------
// 8 lanes per node; each lane strides edges by 8; shfl combine.
__global__ void k5_layer2(const int* __restrict__ rp, const int* __restrict__ esrt,
                          const float4* __restrict__ h2p, const float* __restrict__ ad2,
                          const float* __restrict__ b2,
                          float* __restrict__ out, int N) {
    int t = blockIdx.x * blockDim.x + threadIdx.x;
    int n = t >> 3;
    int sub = t & 7;
    if (n >= N) return;
    float ad = ad2[n];
    float s = 0.f, xx = 0.f, yy = 0.f;
    if (sub == 0) {                            // self-loop
        float4 hv = h2p[n];
        float w = __expf(fminf(lrelu(hv.z + ad), ECLAMP));
        s = w; xx = w * hv.x; yy = w * hv.y;
    }
    int p0 = rp[n], p1 = rp[n + 1];
    for (int p = p0 + sub; p < p1; p += 8) {
        int sn = esrt[p];
        float4 hv = h2p[sn];                   // single 16B random gather
        float w = __expf(fminf(lrelu(hv.z + ad), ECLAMP));
        s += w; xx += w * hv.x; yy += w * hv.y;
    }
#pragma unroll
    for (int msk = 1; msk <= 4; msk <<= 1) {   // combine the 8-lane group
        s  += __shfl_xor(s, msk);
        xx += __shfl_xor(xx, msk);
        yy += __shfl_xor(yy, msk);
    }
    if (sub == 0) {
        float2 o;
        o.x = xx / s + b2[0];
        o.y = yy / s + b2[1];
        reinterpret_cast<float2*>(out)[n] = o;
    }
}

extern "C" void kernel_launch(void* const* d_in, const int* in_sizes, int n_in,
                              void* d_out, int out_size, void* d_ws, size_t ws_size,
                              hipStream_t stream) {
    const float* x      = (const float*)d_in[0];
    const int*   ei     = (const int*)d_in[1];
    const float* W1     = (const float*)d_in[2];
    const float* a_src1 = (const float*)d_in[3];
    const float* a_dst1 = (const float*)d_in[4];
    const float* b1     = (const float*)d_in[5];
    const float* W2     = (const float*)d_in[6];
    const float* a_src2 = (const float*)d_in[7];
    const float* a_dst2 = (const float*)d_in[8];
    const float* b2     = (const float*)d_in[9];
    float* out = (float*)d_out;

    const int N = in_sizes[0] / 4;
    const int E = in_sizes[1] / 2;
    const int* srcp = ei;
    const int* dstp = ei + E;

    const int NB    = (N + BUCKET_MASK) >> BUCKET_SHIFT;   // 128-node buckets
    const int nblkE = (E + EB_CHUNK - 1) / EB_CHUNK;       // edge partition blocks
    const int M     = NB * nblkE;
    const int nb2   = (M + SCAN_CHUNK - 1) / SCAN_CHUNK;

    // workspace layout (h2p first for 16B alignment)
    char* w = (char*)d_ws;
    float4* h2p  = (float4*)w;  w += (size_t)N * sizeof(float4);
    float*  as1  = (float*)w;   w += (size_t)N * 2 * sizeof(float);
    float*  ad1  = (float*)w;   w += (size_t)N * 2 * sizeof(float);
    float*  ad2  = (float*)w;   w += (size_t)N * sizeof(float);
    int* rp     = (int*)w;      w += (size_t)(N + 4) * sizeof(int);
    int* cmatT  = (int*)w;      w += (size_t)M * sizeof(int);
    int* cscan  = (int*)w;      w += (size_t)M * sizeof(int);
    int* bsum   = (int*)w;      w += (size_t)(nb2 + 4) * sizeof(int);
    int* bscan  = (int*)w;      w += (size_t)(nb2 + 4) * sizeof(int);
    unsigned int* ebuf = (unsigned int*)w;  w += (size_t)E * sizeof(unsigned int);
    int* esrt   = (int*)w;      w += (size_t)E * sizeof(int);

    const int BT = 256;
    k0_prep1<<<((size_t)N * 32 + BT - 1) / BT, BT, 0, stream>>>(
        x, W1, a_src1, a_dst1, as1, ad1, N);
    p1_hist<<<nblkE, 256, 0, stream>>>(dstp, cmatT, E, NB, nblkE);
    k2a_partials<<<nb2, 256, 0, stream>>>(cmatT, bsum, M);
    k2b_scanb<<<1, 1024, 0, stream>>>(bsum, bscan, nb2);
    k2c_scan<<<nb2, 256, 0, stream>>>(cmatT, bscan, cscan, M);
    p3_scatter<<<nblkE, 256, 0, stream>>>(srcp, dstp, cscan, ebuf, E, NB, nblkE);
    p4_csr<<<NB, 256, 0, stream>>>(ebuf, cscan, rp, esrt, N, E, NB, nblkE);
    k4_layer1<<<((size_t)N * 8 + BT - 1) / BT, BT, 0, stream>>>(
        rp, esrt, x, as1, ad1, b1, W1, W2, a_src2, a_dst2, h2p, ad2, N);
    k5_layer2<<<((size_t)N * 8 + BT - 1) / BT, BT, 0, stream>>>(
        rp, esrt, h2p, ad2, b2, out, N);
}

// Round 13
// 182.589 us; speedup vs baseline: 1.5053x; 1.0011x over previous
//
#include <hip/hip_runtime.h>
#include <math.h>

#define NEG_SLOPE 0.2f
#define SCAN_CHUNK 2048     // per-block elements in hierarchical scan (256 thr * 8)
#define ECLAMP 80.0f        // exp() inf-safety clamp (never hit statistically)
#define BUCKET_SHIFT 7      // 128 nodes per bucket
#define BUCKET_MASK 127
#define NPB 128             // nodes per bucket
#define NBMAX 1024          // max buckets (N <= 131072)
#define EB_CHUNK 2048       // edges per partition block (256 thr * 8)
#define P4_MAXIT 16         // register-captured edges/thread: cap 4096/bucket (+45 sigma)

__device__ __forceinline__ float lrelu(float e) {
    return e > 0.f ? e : NEG_SLOPE * e;
}

// ---------------- Layer-1 node prep: as1[N,2], ad1[N,2] (h1 never stored) ---
__global__ void k0_prep1(const float* __restrict__ x,
                         const float* __restrict__ W1,
                         const float* __restrict__ a_src1,
                         const float* __restrict__ a_dst1,
                         float* __restrict__ as1,
                         float* __restrict__ ad1,
                         int N) {
    int t = blockIdx.x * blockDim.x + threadIdx.x;
    int n = t >> 5;
    int c = t & 31;
    if (n >= N) return;
    const float4 xv = reinterpret_cast<const float4*>(x)[n];
    float h = xv.x * W1[c] + xv.y * W1[32 + c] + xv.z * W1[64 + c] + xv.w * W1[96 + c];
    float ts = h * a_src1[c];
    float td = h * a_dst1[c];
#pragma unroll
    for (int m = 8; m >= 1; m >>= 1) {
        ts += __shfl_xor(ts, m);
        td += __shfl_xor(td, m);
    }
    if ((c & 15) == 0) {
        int hh = c >> 4;
        as1[n * 2 + hh] = ts;
        ad1[n * 2 + hh] = td;
    }
}

// ---------------- edge partition: two-level counting sort -------------------
__global__ void p1_hist(const int* __restrict__ dst, int* __restrict__ cmatT,
                        int E, int NB, int nblkE) {
    __shared__ int cnt[NBMAX];
    const int blk = blockIdx.x, tid = threadIdx.x;
    for (int b = tid; b < NB; b += 256) cnt[b] = 0;
    __syncthreads();
    int base = blk * EB_CHUNK;
    int end = min(base + EB_CHUNK, E);
    for (int e = base + tid; e < end; e += 256)
        atomicAdd(&cnt[dst[e] >> BUCKET_SHIFT], 1);
    __syncthreads();
    for (int b = tid; b < NB; b += 256)
        cmatT[(size_t)b * nblkE + blk] = cnt[b];
}

// --------- hierarchical exclusive scan (generic, over n ints) ---------------
__global__ void k2a_partials(const int* __restrict__ in, int* __restrict__ bsum, int n) {
    __shared__ int ws[4];
    const int tid = threadIdx.x;
    const int lane = tid & 63, wid = tid >> 6;
    int base = blockIdx.x * SCAN_CHUNK + tid * 8;
    int lsum = 0;
#pragma unroll
    for (int i = 0; i < 8; ++i) {
        int idx = base + i;
        lsum += (idx < n) ? in[idx] : 0;
    }
#pragma unroll
    for (int m = 32; m >= 1; m >>= 1) lsum += __shfl_xor(lsum, m);
    if (lane == 0) ws[wid] = lsum;
    __syncthreads();
    if (tid == 0) bsum[blockIdx.x] = ws[0] + ws[1] + ws[2] + ws[3];
}

__global__ void k2b_scanb(const int* __restrict__ bsum, int* __restrict__ bscan, int nb) {
    __shared__ int wsum[16];
    const int tid = threadIdx.x;
    const int lane = tid & 63, wid = tid >> 6;
    int carry = 0;
    for (int base = 0; base < nb; base += 1024) {
        int i = base + tid;
        int v = (i < nb) ? bsum[i] : 0;
        int xx = v;
#pragma unroll
        for (int off = 1; off < 64; off <<= 1) {
            int t = __shfl_up(xx, off);
            if (lane >= off) xx += t;
        }
        if (lane == 63) wsum[wid] = xx;
        __syncthreads();
        int woff = 0;
        for (int w = 0; w < wid; ++w) woff += wsum[w];
        if (i < nb) bscan[i] = carry + woff + xx - v;
        int tot = 0;
        for (int w = 0; w < 16; ++w) tot += wsum[w];
        carry += tot;
        __syncthreads();
    }
}

__global__ void k2c_scan(const int* __restrict__ in, const int* __restrict__ bscan,
                         int* __restrict__ out, int n) {
    __shared__ int ws[4];
    const int tid = threadIdx.x;
    const int lane = tid & 63, wid = tid >> 6;
    int base = blockIdx.x * SCAN_CHUNK + tid * 8;
    int v[8], pre[8];
    int lsum = 0;
#pragma unroll
    for (int i = 0; i < 8; ++i) {
        int idx = base + i;
        v[i] = (idx < n) ? in[idx] : 0;
        pre[i] = lsum;
        lsum += v[i];
    }
    int xs = lsum;
#pragma unroll
    for (int off = 1; off < 64; off <<= 1) {
        int t = __shfl_up(xs, off);
        if (lane >= off) xs += t;
    }
    if (lane == 63) ws[wid] = xs;
    __syncthreads();
    int woff = 0;
    for (int w = 0; w < wid; ++w) woff += ws[w];
    int off0 = bscan[blockIdx.x] + woff + xs - lsum;
#pragma unroll
    for (int i = 0; i < 8; ++i) {
        int idx = base + i;
        if (idx < n) out[idx] = off0 + pre[i];
    }
}

// P3: scatter edges into bucket-partitioned ebuf via LDS cursors
__global__ void p3_scatter(const int* __restrict__ src, const int* __restrict__ dst,
                           const int* __restrict__ cscan, unsigned int* __restrict__ ebuf,
                           int E, int NB, int nblkE) {
    __shared__ int cur[NBMAX];
    const int blk = blockIdx.x, tid = threadIdx.x;
    for (int b = tid; b < NB; b += 256)
        cur[b] = cscan[(size_t)b * nblkE + blk];
    __syncthreads();
    int base = blk * EB_CHUNK;
    int end = min(base + EB_CHUNK, E);
    for (int e = base + tid; e < end; e += 256) {
        int d = dst[e];
        int b = d >> BUCKET_SHIFT;
        int pos = atomicAdd(&cur[b], 1);
        ebuf[pos] = (unsigned int)src[e] | ((unsigned int)(d & BUCKET_MASK) << 24);
    }
}

// P4: per-bucket CSR finalize, single atomic pass with register-held ranks
__global__ void p4_csr(const unsigned int* __restrict__ ebuf,
                       const int* __restrict__ cscan,
                       int* __restrict__ rp, int* __restrict__ esrt,
                       int N, int E, int NB, int nblkE) {
    __shared__ int degl[NPB];
    __shared__ int base_[NPB];
    __shared__ int curl[NPB];
    __shared__ int wsum[4];
    const int b = blockIdx.x, tid = threadIdx.x;
    const int lane = tid & 63, wid = tid >> 6;
    int bstart = cscan[(size_t)b * nblkE];
    int bend = (b + 1 < NB) ? cscan[(size_t)(b + 1) * nblkE] : E;
    int cnt = bend - bstart;
    if (tid < NPB) degl[tid] = 0;
    __syncthreads();
    // pass A: count + capture (edge, rank) in registers
    unsigned int evs[P4_MAXIT];
    int rks[P4_MAXIT];
#pragma unroll
    for (int it = 0; it < P4_MAXIT; ++it) {
        int i = it * 256 + tid;
        if (i < cnt) {
            unsigned int ev = ebuf[bstart + i];
            evs[it] = ev;
            rks[it] = atomicAdd(&degl[ev >> 24], 1);
        }
    }
    for (int i = P4_MAXIT * 256 + tid; i < cnt; i += 256)    // overflow: count only
        atomicAdd(&degl[ebuf[bstart + i] >> 24], 1);
    __syncthreads();
    // exclusive scan of degl -> per-node base offsets
    int v = (tid < NPB) ? degl[tid] : 0;
    int xs = v;
#pragma unroll
    for (int off = 1; off < 64; off <<= 1) {
        int t = __shfl_up(xs, off);
        if (lane >= off) xs += t;
    }
    if (lane == 63) wsum[wid] = xs;
    __syncthreads();
    int woff = 0;
    for (int w = 0; w < wid; ++w) woff += wsum[w];
    int excl = woff + xs - v;
    int node = (b << BUCKET_SHIFT) + tid;
    if (tid < NPB) {
        if (node < N) rp[node] = bstart + excl;
        base_[tid] = bstart + excl;
    }
    if (b == 0 && tid == 0) rp[N] = E;
    __syncthreads();
    if (cnt <= P4_MAXIT * 256) {
        // write from registers: pos = base_[dl] + rank (no atomics)
#pragma unroll
        for (int it = 0; it < P4_MAXIT; ++it) {
            int i = it * 256 + tid;
            if (i < cnt) {
                unsigned int ev = evs[it];
                esrt[base_[ev >> 24] + rks[it]] = (int)(ev & 0x00FFFFFFu);
            }
        }
    } else {
        // statistically-unreachable fallback: cursor-atomic full re-read
        if (tid < NPB) curl[tid] = base_[tid];
        __syncthreads();
        for (int i = tid; i < cnt; i += 256) {
            unsigned int ev = ebuf[bstart + i];
            int pos = atomicAdd(&curl[ev >> 24], 1);
            esrt[pos] = (int)(ev & 0x00FFFFFFu);
        }
    }
}

// ---------------- Layer-1 aggregate, edge-per-lane + fused epilogue ---------
// 8 lanes per node; lane j owns edges p0+j, p0+j+8, ... Each edge: one float2
// as1 gather + one float4 x gather; both heads computed per lane. 10 partial
// sums reduced over the 8-lane group; fused /s, @W1, +b1, ELU, @W2 epilogue.
__global__ void k4_layer1(const int* __restrict__ rp, const int* __restrict__ esrt,
                          const float* __restrict__ x, const float* __restrict__ as1,
                          const float* __restrict__ ad1, const float* __restrict__ b1,
                          const float* __restrict__ W1,
                          const float* __restrict__ W2, const float* __restrict__ a_src2,
                          const float* __restrict__ a_dst2,
                          float4* __restrict__ h2p, float* __restrict__ ad2,
                          int N) {
    int t = blockIdx.x * blockDim.x + threadIdx.x;
    int n = t >> 3;
    int j = t & 7;
    if (n >= N) return;
    const float2* as1v = reinterpret_cast<const float2*>(as1);
    const float2* ad1v = reinterpret_cast<const float2*>(ad1);
    const float4* x4 = reinterpret_cast<const float4*>(x);
    float2 adv = ad1v[n];
    float s0 = 0.f, s1 = 0.f;
    float g00 = 0.f, g01 = 0.f, g02 = 0.f, g03 = 0.f;
    float g10 = 0.f, g11 = 0.f, g12 = 0.f, g13 = 0.f;
    if (j == 0) {                               // self-loop once per node
        float2 av = as1v[n];
        float4 xv = x4[n];
        float w0 = __expf(fminf(lrelu(av.x + adv.x), ECLAMP));
        float w1 = __expf(fminf(lrelu(av.y + adv.y), ECLAMP));
        s0 = w0; s1 = w1;
        g00 = w0 * xv.x; g01 = w0 * xv.y; g02 = w0 * xv.z; g03 = w0 * xv.w;
        g10 = w1 * xv.x; g11 = w1 * xv.y; g12 = w1 * xv.z; g13 = w1 * xv.w;
    }
    int p0 = rp[n], p1 = rp[n + 1];
    for (int p = p0 + j; p < p1; p += 8) {
        int sn = esrt[p];
        float2 av = as1v[sn];                   // 8B gather
        float4 xv = x4[sn];                     // 16B gather
        float w0 = __expf(fminf(lrelu(av.x + adv.x), ECLAMP));
        float w1 = __expf(fminf(lrelu(av.y + adv.y), ECLAMP));
        s0 += w0; s1 += w1;
        g00 += w0 * xv.x; g01 += w0 * xv.y; g02 += w0 * xv.z; g03 += w0 * xv.w;
        g10 += w1 * xv.x; g11 += w1 * xv.y; g12 += w1 * xv.z; g13 += w1 * xv.w;
    }
#pragma unroll
    for (int msk = 1; msk <= 4; msk <<= 1) {    // reduce 10 partials over 8 lanes
        s0 += __shfl_xor(s0, msk);   s1 += __shfl_xor(s1, msk);
        g00 += __shfl_xor(g00, msk); g01 += __shfl_xor(g01, msk);
        g02 += __shfl_xor(g02, msk); g03 += __shfl_xor(g03, msk);
        g10 += __shfl_xor(g10, msk); g11 += __shfl_xor(g11, msk);
        g12 += __shfl_xor(g12, msk); g13 += __shfl_xor(g13, msk);
    }
    float r0 = 1.f / s0, r1 = 1.f / s1;
    // lane j handles channels c = j*4..j*4+3, all in head (j>>2) — select
    // the matching head's aggregated x into named registers (no runtime idx)
    bool h1sel = (j >= 4);
    float ax = h1sel ? g10 * r1 : g00 * r0;
    float ay = h1sel ? g11 * r1 : g01 * r0;
    float az = h1sel ? g12 * r1 : g02 * r0;
    float aw = h1sel ? g13 * r1 : g03 * r0;
    float t0 = 0.f, t1 = 0.f;
#pragma unroll
    for (int jj = 0; jj < 4; ++jj) {
        int c = j * 4 + jj;
        float o = b1[c] + ax * W1[c] + ay * W1[32 + c]
                + az * W1[64 + c] + aw * W1[96 + c];
        o = o > 0.f ? o : expm1f(o);            // ELU
        t0 += o * W2[c * 2 + 0];
        t1 += o * W2[c * 2 + 1];
    }
#pragma unroll
    for (int msk = 1; msk <= 4; msk <<= 1) {
        t0 += __shfl_xor(t0, msk);
        t1 += __shfl_xor(t1, msk);
    }
    if (j == 0) {
        float as2v = t0 * a_src2[0] + t1 * a_src2[1];
        float ad2v = t0 * a_dst2[0] + t1 * a_dst2[1];
        h2p[n] = make_float4(t0, t1, as2v, 0.f);
        ad2[n] = ad2v;
    }
}

// ---------------- Layer-2 aggregate → output --------------------------------
// 8 lanes per node; each lane strides edges by 8; shfl combine.
__global__ void k5_layer2(const int* __restrict__ rp, const int* __restrict__ esrt,
                          const float4* __restrict__ h2p, const float* __restrict__ ad2,
                          const float* __restrict__ b2,
                          float* __restrict__ out, int N) {
    int t = blockIdx.x * blockDim.x + threadIdx.x;
    int n = t >> 3;
    int sub = t & 7;
    if (n >= N) return;
    float ad = ad2[n];
    float s = 0.f, xx = 0.f, yy = 0.f;
    if (sub == 0) {                            // self-loop
        float4 hv = h2p[n];
        float w = __expf(fminf(lrelu(hv.z + ad), ECLAMP));
        s = w; xx = w * hv.x; yy = w * hv.y;
    }
    int p0 = rp[n], p1 = rp[n + 1];
    for (int p = p0 + sub; p < p1; p += 8) {
        int sn = esrt[p];
        float4 hv = h2p[sn];                   // single 16B random gather
        float w = __expf(fminf(lrelu(hv.z + ad), ECLAMP));
        s += w; xx += w * hv.x; yy += w * hv.y;
    }
#pragma unroll
    for (int msk = 1; msk <= 4; msk <<= 1) {   // combine the 8-lane group
        s  += __shfl_xor(s, msk);
        xx += __shfl_xor(xx, msk);
        yy += __shfl_xor(yy, msk);
    }
    if (sub == 0) {
        float2 o;
        o.x = xx / s + b2[0];
        o.y = yy / s + b2[1];
        reinterpret_cast<float2*>(out)[n] = o;
    }
}

extern "C" void kernel_launch(void* const* d_in, const int* in_sizes, int n_in,
                              void* d_out, int out_size, void* d_ws, size_t ws_size,
                              hipStream_t stream) {
    const float* x      = (const float*)d_in[0];
    const int*   ei     = (const int*)d_in[1];
    const float* W1     = (const float*)d_in[2];
    const float* a_src1 = (const float*)d_in[3];
    const float* a_dst1 = (const float*)d_in[4];
    const float* b1     = (const float*)d_in[5];
    const float* W2     = (const float*)d_in[6];
    const float* a_src2 = (const float*)d_in[7];
    const float* a_dst2 = (const float*)d_in[8];
    const float* b2     = (const float*)d_in[9];
    float* out = (float*)d_out;

    const int N = in_sizes[0] / 4;
    const int E = in_sizes[1] / 2;
    const int* srcp = ei;
    const int* dstp = ei + E;

    const int NB    = (N + BUCKET_MASK) >> BUCKET_SHIFT;   // 128-node buckets
    const int nblkE = (E + EB_CHUNK - 1) / EB_CHUNK;       // edge partition blocks
    const int M     = NB * nblkE;
    const int nb2   = (M + SCAN_CHUNK - 1) / SCAN_CHUNK;

    // workspace layout (h2p first for 16B alignment)
    char* w = (char*)d_ws;
    float4* h2p  = (float4*)w;  w += (size_t)N * sizeof(float4);
    float*  as1  = (float*)w;   w += (size_t)N * 2 * sizeof(float);
    float*  ad1  = (float*)w;   w += (size_t)N * 2 * sizeof(float);
    float*  ad2  = (float*)w;   w += (size_t)N * sizeof(float);
    int* rp     = (int*)w;      w += (size_t)(N + 4) * sizeof(int);
    int* cmatT  = (int*)w;      w += (size_t)M * sizeof(int);
    int* cscan  = (int*)w;      w += (size_t)M * sizeof(int);
    int* bsum   = (int*)w;      w += (size_t)(nb2 + 4) * sizeof(int);
    int* bscan  = (int*)w;      w += (size_t)(nb2 + 4) * sizeof(int);
    unsigned int* ebuf = (unsigned int*)w;  w += (size_t)E * sizeof(unsigned int);
    int* esrt   = (int*)w;      w += (size_t)E * sizeof(int);

    const int BT = 256;
    k0_prep1<<<((size_t)N * 32 + BT - 1) / BT, BT, 0, stream>>>(
        x, W1, a_src1, a_dst1, as1, ad1, N);
    p1_hist<<<nblkE, 256, 0, stream>>>(dstp, cmatT, E, NB, nblkE);
    k2a_partials<<<nb2, 256, 0, stream>>>(cmatT, bsum, M);
    k2b_scanb<<<1, 1024, 0, stream>>>(bsum, bscan, nb2);
    k2c_scan<<<nb2, 256, 0, stream>>>(cmatT, bscan, cscan, M);
    p3_scatter<<<nblkE, 256, 0, stream>>>(srcp, dstp, cscan, ebuf, E, NB, nblkE);
    p4_csr<<<NB, 256, 0, stream>>>(ebuf, cscan, rp, esrt, N, E, NB, nblkE);
    k4_layer1<<<((size_t)N * 8 + BT - 1) / BT, BT, 0, stream>>>(
        rp, esrt, x, as1, ad1, b1, W1, W2, a_src2, a_dst2, h2p, ad2, N);
    k5_layer2<<<((size_t)N * 8 + BT - 1) / BT, BT, 0, stream>>>(
        rp, esrt, h2p, ad2, b2, out, N);
}